// Round 8
// baseline (537.030 us; speedup 1.0000x reference)
//
#include <hip/hip_runtime.h>

// Problem: nearest = memory[argmax_m cosine(x_row, memory_m)], plus copy of x.
//   x: 65536 x 1024 f32, memory: 40 x 1024 f32, out = [nearest | x-copy]
//
// R8 = R7 with the nontemporal-store type fix (ext_vector_type float4).
// Structure: ZERO barriers. Block = ONE wave = 64 x-rows (lane = row).
// Wave-private LDS transpose slice (in-order DS => no sync). Wave owns ALL 40
// m's (acc[40] in VGPR) => no cross-wave merge. m-operands are wave-uniform
// scalar loads (lgkmcnt path); only the 8 prefetched x-loads ride vmcnt, and
// their wait lands after the ~2700-cycle FMA block => hidden. Stores are
// nontemporal and never drained. Evidence: R1-R5 barrier convoy capped BW at
// ~2 TB/s (fill kernel does 6.7 TB/s); occupancy x2 and m-path changes were null.
//
// d_ws layout (bytes):
//   [0,   320) : double inv64[40]
//   [320, 480) : float  inv32[40]
//   [512, 8704): unsigned long long flagbits[1024] (one bit/x-row, 64/word)

#define DIM 1024
#define NMEM 40

typedef float vfloat4 __attribute__((ext_vector_type(4)));  // nt-store-compatible

constexpr float TAU = 2.5e-4f;   // normalized top-2 gap below which f64 re-resolve

// ---------------- Kernel 1: memory-row inverse norms (f32 + f64) ----------------
__global__ __launch_bounds__(64) void k_norms(const float* __restrict__ mem,
                                              double* __restrict__ inv64,
                                              float* __restrict__ inv32) {
  const int m = blockIdx.x;      // 40 blocks, 1 wave each
  const int lane = threadIdx.x;
  const float* __restrict__ row = mem + (size_t)m * DIM;
  double s = 0.0;
#pragma unroll
  for (int i = 0; i < DIM / 64; ++i) {
    double v = (double)row[lane + 64 * i];
    s = fma(v, v, s);
  }
#pragma unroll
  for (int off = 32; off > 0; off >>= 1) s += __shfl_xor(s, off, 64);
  if (lane == 0) {
    double n = sqrt(s);
    n = (n > 1e-8) ? n : 1e-8;
    inv64[m] = 1.0 / n;
    inv32[m] = (float)(1.0 / n);
  }
}

// ---------------- Kernel 2: fused sims + argmax + gather + x-copy ----------------
__global__ __launch_bounds__(64) void k_main(const float* __restrict__ x,
                                             const float* __restrict__ mem,
                                             const float* __restrict__ inv32,
                                             float* __restrict__ out_near,
                                             float* __restrict__ out_x,
                                             unsigned long long* __restrict__ flagbits) {
  __shared__ vfloat4 xt[64 * 9];  // 64 rows x 8 slots, +1 pad (measured 0 conflicts)
  __shared__ int     amax[64];

  const int lane = threadIdx.x;   // block == one wave
  const int rowbase = blockIdx.x * 64;

  const vfloat4* __restrict__ x4 = (const vfloat4*)x + (size_t)rowbase * (DIM / 4);
  vfloat4* __restrict__ ox4      = (vfloat4*)out_x  + (size_t)rowbase * (DIM / 4);

  // staging map: instr i covers rows {rS+8i}, slot sS -> 8 full 128B lines/instr
  const int rS = lane >> 3, sS = lane & 7;

  float acc[NMEM];
#pragma unroll
  for (int m = 0; m < NMEM; ++m) acc[m] = 0.f;
  float nx = 0.f;                 // ||x_row||^2, lane-local (lane owns whole row)

  vfloat4 g[8];
#pragma unroll
  for (int i = 0; i < 8; ++i)     // prologue: chunk 0 loads
    g[i] = x4[(size_t)(rS + 8 * i) * (DIM / 4) + sS];

#pragma unroll 1                   // keep body single-copy (I-cache)
  for (int kc = 0; kc < DIM / 32; ++kc) {
    // stage current chunk from g: x-copy store (nt, never drained) + LDS write
#pragma unroll
    for (int i = 0; i < 8; ++i) {
      __builtin_nontemporal_store(g[i], &ox4[(size_t)(rS + 8 * i) * (DIM / 4) + kc * 8 + sS]);
      xt[(rS + 8 * i) * 9 + sS] = g[i];    // operands latched at issue; g reusable after
    }
    // issue next chunk's loads immediately; FMA block below covers their latency
    if (kc < DIM / 32 - 1) {
#pragma unroll
      for (int i = 0; i < 8; ++i)
        g[i] = x4[(size_t)(rS + 8 * i) * (DIM / 4) + (kc + 1) * 8 + sS];
    }
    // lane's row-chunk (DS in-order within wave: sees this chunk's writes)
    vfloat4 xv[8];
#pragma unroll
    for (int k4 = 0; k4 < 8; ++k4) xv[k4] = xt[lane * 9 + k4];
#pragma unroll
    for (int k4 = 0; k4 < 8; ++k4)
      nx = fmaf(xv[k4].x, xv[k4].x, fmaf(xv[k4].y, xv[k4].y,
           fmaf(xv[k4].z, xv[k4].z, fmaf(xv[k4].w, xv[k4].w, nx))));
    // dots, m-major: mem operands wave-uniform -> scalar loads (lgkm, not vmcnt)
    const float* __restrict__ mk = mem + kc * 32;
#pragma unroll
    for (int m = 0; m < NMEM; ++m) {
      const vfloat4* __restrict__ mp = (const vfloat4*)(mk + (size_t)m * DIM);
      float a = acc[m];
#pragma unroll
      for (int k4 = 0; k4 < 8; ++k4) {
        vfloat4 mv = mp[k4];
        a = fmaf(xv[k4].x, mv.x, fmaf(xv[k4].y, mv.y,
            fmaf(xv[k4].z, mv.z, fmaf(xv[k4].w, mv.w, a))));
      }
      acc[m] = a;
    }
  }

  // in-lane top-2 over all 40 m's (ascending m, strict > keeps lowest index)
  float v1 = -3.4e38f, v2 = -3.4e38f;
  int i1 = 0;
#pragma unroll
  for (int m = 0; m < NMEM; ++m) {
    float v = acc[m] * inv32[m];  // ||x|| factor common to all m -> argmax-invariant
    if (v > v1) { v2 = v1; v1 = v; i1 = m; }
    else if (v > v2) v2 = v;
  }
  float gap = (v1 - v2) * rsqrtf(fmaxf(nx, 1e-30f));  // normalized top-2 gap
  bool flag = !(gap >= TAU);                           // NaN-safe: NaN -> flagged
  unsigned long long mask = __ballot(flag);
  if (lane == 0) flagbits[blockIdx.x] = mask;          // all 1024 words written every call

  amax[lane] = i1;                // wave-internal publish; DS in-order, no sync needed

  // gather-copy memory[amax[r]] -> out_near, coalesced; src base scalarized
  vfloat4* __restrict__ on4 = (vfloat4*)out_near + (size_t)rowbase * (DIM / 4);
  const vfloat4* __restrict__ m4 = (const vfloat4*)mem;
#pragma unroll 1
  for (int r = 0; r < 64; ++r) {
    int am = __builtin_amdgcn_readfirstlane(amax[r]);  // uniform per r
    const vfloat4* __restrict__ src = m4 + (size_t)am * (DIM / 4);
    vfloat4* __restrict__ dst = on4 + (size_t)r * (DIM / 4);
#pragma unroll
    for (int j = 0; j < 4; ++j) {
      vfloat4 v = src[lane + 64 * j];
      __builtin_nontemporal_store(v, &dst[lane + 64 * j]);
    }
  }
}

// ---------------- Kernel 3: f64 re-resolution of razor-thin rows ----------------
__global__ __launch_bounds__(256) void k_refine(const float* __restrict__ x,
                                                const float* __restrict__ mem,
                                                const double* __restrict__ inv64,
                                                const unsigned long long* __restrict__ flagbits,
                                                float* __restrict__ out_near) {
  unsigned long long mask = flagbits[blockIdx.x];
  if (mask == 0ull) return;                 // uniform; nearly all blocks exit here
  const int tid = threadIdx.x;
  const int lane = tid & 63;
  const int wid = tid >> 6;
  __shared__ double bval[4];
  __shared__ int bidx[4];
  while (mask) {
    int r = __ffsll(mask) - 1;
    mask &= (mask - 1ull);
    int row = blockIdx.x * 64 + r;
    const float* __restrict__ xr = x + (size_t)row * DIM;
    double xd[16];
#pragma unroll
    for (int i = 0; i < 16; ++i) xd[i] = (double)xr[lane + 64 * i];
    double best = -1e300;
    int bi = 0;
    for (int q = 0; q < 10; ++q) {
      int m = wid * 10 + q;
      const float* __restrict__ mr = mem + (size_t)m * DIM;
      double s = 0.0;
#pragma unroll
      for (int i = 0; i < 16; ++i) s = fma(xd[i], (double)mr[lane + 64 * i], s);
#pragma unroll
      for (int off = 32; off > 0; off >>= 1) s += __shfl_xor(s, off, 64);
      double v = s * inv64[m];              // identical (bitwise) across lanes
      if (v > best) { best = v; bi = m; }   // strict > keeps lowest m on ties
    }
    if (lane == 0) { bval[wid] = best; bidx[wid] = bi; }
    __syncthreads();
    double g = bval[0];
    int gi = bidx[0];
#pragma unroll
    for (int gg = 1; gg < 4; ++gg) {
      if (bval[gg] > g) { g = bval[gg]; gi = bidx[gg]; }
    }
    const float4* __restrict__ src = (const float4*)mem + (size_t)gi * (DIM / 4);
    float4* __restrict__ dst = (float4*)out_near + (size_t)row * (DIM / 4);
    dst[tid] = src[tid];                    // 256 x 16B = full row, coalesced
    __syncthreads();                        // LDS reuse guard for next flagged row
  }
}

extern "C" void kernel_launch(void* const* d_in, const int* in_sizes, int n_in,
                              void* d_out, int out_size, void* d_ws, size_t ws_size,
                              hipStream_t stream) {
  const float* x   = (const float*)d_in[0];
  const float* mem = (const float*)d_in[1];
  // d_in[2] = top_k (unused: reference only consumes idx[:,0], i.e. the argmax)

  const int n_rows = in_sizes[0] / DIM;          // 65536
  float* out_near = (float*)d_out;
  float* out_x    = (float*)d_out + (size_t)n_rows * DIM;

  double* inv64 = (double*)d_ws;
  float*  inv32 = (float*)((char*)d_ws + 320);
  unsigned long long* flagbits = (unsigned long long*)((char*)d_ws + 512);

  hipLaunchKernelGGL(k_norms,  dim3(NMEM), dim3(64), 0, stream, mem, inv64, inv32);
  hipLaunchKernelGGL(k_main,   dim3(n_rows / 64), dim3(64), 0, stream,
                     x, mem, inv32, out_near, out_x, flagbits);
  hipLaunchKernelGGL(k_refine, dim3(n_rows / 64), dim3(256), 0, stream,
                     x, mem, inv64, flagbits, out_near);
}

// Round 9
// 260.228 us; speedup vs baseline: 2.0637x; 2.0637x over previous
//
#include <hip/hip_runtime.h>

// Problem: nearest = memory[argmax_m cosine(x_row, memory_m)], plus copy of x.
//   x: 65536 x 1024 f32, memory: 40 x 1024 f32, out = [nearest | x-copy]
//
// R9: MFMA split-f32 path. x and (normalized) memory are each split into
// hi+lo bf16; sims = 4 bf16-MFMA passes (16x16x32) accumulating f32. Error
// ~2e-5 << TAU=2.5e-4, so the f64 re-resolve net (k_refine) preserves
// exactness of the argmax. Hot loop has NO LDS staging, NO barriers, NO
// broadcast m-loads (the R1-R8 bottlenecks): A-frags are coalesced global
// loads of x, B-frags are distinct-per-lane L2-resident loads.
//
// d_ws layout (bytes):
//   [0,      320) : double inv64[40]
//   [320,    480) : float  inv32[40]
//   [512,  16896) : uint flagbits[4096]  (16-bit mask per 16-row wave)
//   [32768,131072): ushort bhi[48][1024] (bf16 hi of mem*inv32, rows 40-47 = 0)
//   [131072,229376): ushort blo[48][1024] (bf16 lo)

#define DIM 1024
#define NMEM 40

typedef float  vf4 __attribute__((ext_vector_type(4)));
typedef float  f4a __attribute__((ext_vector_type(4)));
typedef short  s8v __attribute__((ext_vector_type(8)));

union FragU { s8v v; unsigned int u[4]; };

constexpr float TAU = 2.5e-4f;   // normalized top-2 gap below which f64 re-resolve

// ---------------- Kernel 1: memory-row inverse norms (f32 + f64) ----------------
__global__ __launch_bounds__(64) void k_norms(const float* __restrict__ mem,
                                              double* __restrict__ inv64,
                                              float* __restrict__ inv32) {
  const int m = blockIdx.x;      // 40 blocks, 1 wave each
  const int lane = threadIdx.x;
  const float* __restrict__ row = mem + (size_t)m * DIM;
  double s = 0.0;
#pragma unroll
  for (int i = 0; i < DIM / 64; ++i) {
    double v = (double)row[lane + 64 * i];
    s = fma(v, v, s);
  }
#pragma unroll
  for (int off = 32; off > 0; off >>= 1) s += __shfl_xor(s, off, 64);
  if (lane == 0) {
    double n = sqrt(s);
    n = (n > 1e-8) ? n : 1e-8;
    inv64[m] = 1.0 / n;
    inv32[m] = (float)(1.0 / n);
  }
}

// ---------------- Kernel 1b: split normalized memory into bf16 hi/lo ----------------
__global__ __launch_bounds__(256) void k_prep(const float* __restrict__ mem,
                                              const float* __restrict__ inv32,
                                              unsigned short* __restrict__ bhi,
                                              unsigned short* __restrict__ blo) {
  const int m = blockIdx.x;            // 0..47 (40 real + 8 zero-pad)
  const int k0 = threadIdx.x * 4;      // 1024/256 = 4 elems/thread
  if (m < NMEM) {
    const float s = inv32[m];
#pragma unroll
    for (int j = 0; j < 4; ++j) {
      float w = mem[(size_t)m * DIM + k0 + j] * s;
      unsigned int u = __builtin_bit_cast(unsigned int, w);
      bhi[(size_t)m * DIM + k0 + j] = (unsigned short)(u >> 16);
      float hf = __builtin_bit_cast(float, u & 0xFFFF0000u);
      float lo = w - hf;
      blo[(size_t)m * DIM + k0 + j] =
          (unsigned short)(__builtin_bit_cast(unsigned int, lo) >> 16);
    }
  } else {
#pragma unroll
    for (int j = 0; j < 4; ++j) {
      bhi[(size_t)m * DIM + k0 + j] = 0;
      blo[(size_t)m * DIM + k0 + j] = 0;
    }
  }
}

// ---------------- Kernel 2: MFMA sims + argmax + gather + x-copy ----------------
// Block = 256 thr = 4 independent waves (no barriers). Wave = 16 x-rows.
// A-frag (x): lane holds row (l&15), k-slice (l>>4)*8..+8 -> fully coalesced
// 128B lines. B-frag (mem): lane holds m-col (l&15)+16*tile, same k-slice.
// C layout (m89-verified): lane holds D[(l>>4)*4+j][(l&15)+16*tile].
__global__ __launch_bounds__(256, 4) void k_main(const float* __restrict__ x,
                                                 const float* __restrict__ mem,
                                                 const unsigned short* __restrict__ bhi,
                                                 const unsigned short* __restrict__ blo,
                                                 float* __restrict__ out_near,
                                                 float* __restrict__ out_x,
                                                 unsigned int* __restrict__ flagbits) {
  __shared__ float nxw[4][16];
  __shared__ int   amaxw[4][16];
  __shared__ int   flagw[4][16];

  const int tid  = threadIdx.x;
  const int lane = tid & 63;
  const int w    = __builtin_amdgcn_readfirstlane(tid >> 6);
  const int row  = lane & 15;          // x-row within wave tile / m-col within tile
  const int kg   = lane >> 4;          // k-subslice group (0..3)
  const int rowbase = blockIdx.x * 64 + w * 16;

  const float* __restrict__ xp  = x     + (size_t)(rowbase + row) * DIM + kg * 8;
  float* __restrict__ oxp       = out_x + (size_t)(rowbase + row) * DIM + kg * 8;
  const unsigned short* __restrict__ bp = bhi + (size_t)row * DIM + kg * 8;
  const unsigned short* __restrict__ lp = blo + (size_t)row * DIM + kg * 8;

  f4a acc[3];
#pragma unroll
  for (int t = 0; t < 3; ++t) acc[t] = (f4a){0.f, 0.f, 0.f, 0.f};
  float nx = 0.f;

  vf4 cA0, cA1, nA0, nA1;
  cA0 = *(const vf4*)(xp);
  cA1 = *(const vf4*)(xp + 4);

  auto step = [&](vf4& a0, vf4& a1, vf4& n0, vf4& n1, int t) {
    // B-frags for this K-step (L2-resident, distinct data per lane)
    s8v bh[3], bl[3];
#pragma unroll
    for (int tt = 0; tt < 3; ++tt) {
      bh[tt] = *(const s8v*)(bp + (size_t)tt * 16 * DIM + t * 32);
      bl[tt] = *(const s8v*)(lp + (size_t)tt * 16 * DIM + t * 32);
    }
    if (t < 31) {                       // A prefetch (HBM) into alternate regs
      n0 = *(const vf4*)(xp + (t + 1) * 32);
      n1 = *(const vf4*)(xp + (t + 1) * 32 + 4);
    }
    // x-copy from the same registers (x read exactly once)
    __builtin_nontemporal_store(a0, (vf4*)(oxp + t * 32));
    __builtin_nontemporal_store(a1, (vf4*)(oxp + t * 32 + 4));
    // ||x||^2 partial
    nx = fmaf(a0.x, a0.x, fmaf(a0.y, a0.y, fmaf(a0.z, a0.z, fmaf(a0.w, a0.w, nx))));
    nx = fmaf(a1.x, a1.x, fmaf(a1.y, a1.y, fmaf(a1.z, a1.z, fmaf(a1.w, a1.w, nx))));
    // split f32 -> hi/lo bf16 (truncation; residual ~2^-17)
    FragU ah, al;
    {
      float f[8] = {a0.x, a0.y, a0.z, a0.w, a1.x, a1.y, a1.z, a1.w};
#pragma unroll
      for (int p = 0; p < 4; ++p) {
        unsigned int u0 = __builtin_bit_cast(unsigned int, f[2 * p]);
        unsigned int u1 = __builtin_bit_cast(unsigned int, f[2 * p + 1]);
        ah.u[p] = (u1 & 0xFFFF0000u) | (u0 >> 16);
        float h0 = __builtin_bit_cast(float, u0 & 0xFFFF0000u);
        float h1 = __builtin_bit_cast(float, u1 & 0xFFFF0000u);
        float l0 = f[2 * p] - h0;
        float l1 = f[2 * p + 1] - h1;
        al.u[p] = (__builtin_bit_cast(unsigned int, l1) & 0xFFFF0000u) |
                  (__builtin_bit_cast(unsigned int, l0) >> 16);
      }
    }
    // 4 split passes x 3 N-tiles
#pragma unroll
    for (int tt = 0; tt < 3; ++tt) {
      acc[tt] = __builtin_amdgcn_mfma_f32_16x16x32_bf16(ah.v, bh[tt], acc[tt], 0, 0, 0);
      acc[tt] = __builtin_amdgcn_mfma_f32_16x16x32_bf16(ah.v, bl[tt], acc[tt], 0, 0, 0);
      acc[tt] = __builtin_amdgcn_mfma_f32_16x16x32_bf16(al.v, bh[tt], acc[tt], 0, 0, 0);
      acc[tt] = __builtin_amdgcn_mfma_f32_16x16x32_bf16(al.v, bl[tt], acc[tt], 0, 0, 0);
    }
  };

  for (int t = 0; t < 32; t += 2) {     // explicit double-buffer, static indexing
    step(cA0, cA1, nA0, nA1, t);
    step(nA0, nA1, cA0, cA1, t + 1);
  }

  // ||x||^2: sum the 4 k-groups (lanes l, l^16, l^32, l^48 share row l&15)
  nx += __shfl_xor(nx, 16, 64);
  nx += __shfl_xor(nx, 32, 64);
  if (lane < 16) nxw[w][lane] = nx;

  // per-lane top-2: lane holds sims for rows (l>>4)*4+j, m-cols (l&15)+16t
  float v1[4], v2[4];
  int   i1[4];
#pragma unroll
  for (int j = 0; j < 4; ++j) {
    float c0 = acc[0][j], c1 = acc[1][j];
    float c2 = (row < 8) ? acc[2][j] : -3.4e38f;   // cols 40-47 are pad
    float a1 = c0, a2 = -3.4e38f;
    int   ai = row;
    if (c1 > a1) { a2 = a1; a1 = c1; ai = row + 16; } else a2 = c1;
    if (c2 > a1) { a2 = a1; a1 = c2; ai = row + 32; } else if (c2 > a2) a2 = c2;
    v1[j] = a1; v2[j] = a2; i1[j] = ai;
  }
#pragma unroll
  for (int st = 1; st < 16; st <<= 1) {  // reduce over the 16 lanes of each row-group
#pragma unroll
    for (int j = 0; j < 4; ++j) {
      float o1 = __shfl_xor(v1[j], st, 64);
      float o2 = __shfl_xor(v2[j], st, 64);
      int   oi = __shfl_xor(i1[j], st, 64);
      if (o1 > v1[j]) { v2[j] = fmaxf(v1[j], o2); v1[j] = o1; i1[j] = oi; }
      else            { v2[j] = fmaxf(v2[j], o1); }           // tie -> gap 0 -> flagged
    }
  }
  if ((lane & 15) == 0) {
    const int g = lane >> 4;
#pragma unroll
    for (int j = 0; j < 4; ++j) {
      const int r = 4 * g + j;
      float gap = (v1[j] - v2[j]) * rsqrtf(fmaxf(nxw[w][r], 1e-30f));
      flagw[w][r] = !(gap >= TAU);     // NaN-safe
      amaxw[w][r] = i1[j];
    }
  }
  int flv = flagw[w][lane & 15];
  unsigned long long bmask = __ballot(flv != 0);
  if (lane == 0) flagbits[blockIdx.x * 4 + w] = (unsigned int)(bmask & 0xFFFFull);

  // gather-copy memory[amax] -> out_near (16 rows/wave, coalesced)
  const vf4* __restrict__ m4 = (const vf4*)mem;
#pragma unroll 1
  for (int r = 0; r < 16; ++r) {
    int am = __builtin_amdgcn_readfirstlane(amaxw[w][r]);
    const vf4* __restrict__ src = m4 + (size_t)am * (DIM / 4);
    vf4* __restrict__ dst = (vf4*)out_near + (size_t)(rowbase + r) * (DIM / 4);
#pragma unroll
    for (int j = 0; j < 4; ++j) {
      vf4 v = src[lane + 64 * j];
      __builtin_nontemporal_store(v, &dst[lane + 64 * j]);
    }
  }
}

// ---------------- Kernel 3: f64 re-resolution of razor-thin rows ----------------
__global__ __launch_bounds__(256) void k_refine(const float* __restrict__ x,
                                                const float* __restrict__ mem,
                                                const double* __restrict__ inv64,
                                                const unsigned int* __restrict__ flagbits,
                                                float* __restrict__ out_near) {
  unsigned int mask = flagbits[blockIdx.x];
  if (mask == 0u) return;                   // uniform; nearly all blocks exit
  const int tid = threadIdx.x;
  const int lane = tid & 63;
  const int wid = tid >> 6;
  __shared__ double bval[4];
  __shared__ int bidx[4];
  while (mask) {
    int r = __ffs(mask) - 1;
    mask &= (mask - 1u);
    int rrow = blockIdx.x * 16 + r;
    const float* __restrict__ xr = x + (size_t)rrow * DIM;
    double xd[16];
#pragma unroll
    for (int i = 0; i < 16; ++i) xd[i] = (double)xr[lane + 64 * i];
    double best = -1e300;
    int bi = 0;
    for (int q = 0; q < 10; ++q) {
      int m = wid * 10 + q;
      const float* __restrict__ mr = mem + (size_t)m * DIM;
      double s = 0.0;
#pragma unroll
      for (int i = 0; i < 16; ++i) s = fma(xd[i], (double)mr[lane + 64 * i], s);
#pragma unroll
      for (int off = 32; off > 0; off >>= 1) s += __shfl_xor(s, off, 64);
      double v = s * inv64[m];              // identical (bitwise) across lanes
      if (v > best) { best = v; bi = m; }   // strict > keeps lowest m on ties
    }
    if (lane == 0) { bval[wid] = best; bidx[wid] = bi; }
    __syncthreads();
    double g = bval[0];
    int gi = bidx[0];
#pragma unroll
    for (int gg = 1; gg < 4; ++gg) {
      if (bval[gg] > g) { g = bval[gg]; gi = bidx[gg]; }
    }
    const float4* __restrict__ src = (const float4*)mem + (size_t)gi * (DIM / 4);
    float4* __restrict__ dst = (float4*)out_near + (size_t)rrow * (DIM / 4);
    dst[tid] = src[tid];                    // 256 x 16B = full row, coalesced
    __syncthreads();                        // LDS reuse guard for next flagged row
  }
}

extern "C" void kernel_launch(void* const* d_in, const int* in_sizes, int n_in,
                              void* d_out, int out_size, void* d_ws, size_t ws_size,
                              hipStream_t stream) {
  const float* x   = (const float*)d_in[0];
  const float* mem = (const float*)d_in[1];
  // d_in[2] = top_k (unused: reference only consumes idx[:,0], i.e. the argmax)

  const int n_rows = in_sizes[0] / DIM;          // 65536
  float* out_near = (float*)d_out;
  float* out_x    = (float*)d_out + (size_t)n_rows * DIM;

  double* inv64 = (double*)d_ws;
  float*  inv32 = (float*)((char*)d_ws + 320);
  unsigned int* flagbits = (unsigned int*)((char*)d_ws + 512);
  unsigned short* bhi = (unsigned short*)((char*)d_ws + 32768);
  unsigned short* blo = (unsigned short*)((char*)d_ws + 131072);

  hipLaunchKernelGGL(k_norms, dim3(NMEM), dim3(64), 0, stream, mem, inv64, inv32);
  hipLaunchKernelGGL(k_prep,  dim3(48),   dim3(256), 0, stream, mem, inv32, bhi, blo);
  hipLaunchKernelGGL(k_main,  dim3(n_rows / 64), dim3(256), 0, stream,
                     x, mem, bhi, blo, out_near, out_x, flagbits);
  hipLaunchKernelGGL(k_refine, dim3(n_rows / 16), dim3(256), 0, stream,
                     x, mem, inv64, flagbits, out_near);
}